// Round 1
// baseline (337.194 us; speedup 1.0000x reference)
//
#include <hip/hip_runtime.h>
#include <hip/hip_bf16.h>
#include <math.h>

#define N_TOK 65536
#define DIM   256
#define NEXP  8
#define CAP   65536   // per-expert list capacity (hard upper bound = N)

using frag_ab = __attribute__((ext_vector_type(8))) short;   // 8 bf16
using frag_cd = __attribute__((ext_vector_type(4))) float;   // 4 fp32 acc

__device__ __forceinline__ unsigned short f2bf(float f) {
  unsigned u = __float_as_uint(f);
  u += 0x7FFFu + ((u >> 16) & 1u);   // RNE
  return (unsigned short)(u >> 16);
}

// ---------------- k_prep: Wb=bf16(W); c[e][o]=bias_e . W_e[o]; zero cursors --
__global__ __launch_bounds__(256) void k_prep(
    const float* __restrict__ w,      // expert_weight [E][OUT][D]
    const float* __restrict__ bias,   // expert_bias   [E][D]
    unsigned short* __restrict__ Wb,
    float* __restrict__ c,            // [E][OUT]
    int* __restrict__ cursor) {
  int b = blockIdx.x, tid = threadIdx.x;
  if (b < 512) {
    int gid = b * 256 + tid;                  // 512*256*4 = 524288 floats
    float4 v = ((const float4*)w)[gid];
    ushort4 h; h.x = f2bf(v.x); h.y = f2bf(v.y); h.z = f2bf(v.z); h.w = f2bf(v.w);
    ((ushort4*)Wb)[gid] = h;
    if (b == 0 && tid < 16) cursor[tid] = 0;
  } else {
    int wid = ((b - 512) * 256 + tid) >> 6;   // 0..2047 : one wave per (e,o)
    int lane = tid & 63;
    int e = wid >> 8, o = wid & 255;
    const float* br = bias + e * DIM + lane * 4;
    const float* wr = w + (size_t)(e * 256 + o) * DIM + lane * 4;
    float s = br[0] * wr[0] + br[1] * wr[1] + br[2] * wr[2] + br[3] * wr[3];
    #pragma unroll
    for (int m = 1; m < 64; m <<= 1) s += __shfl_xor(s, m, 64);
    if (lane == 0) c[e * 256 + o] = s;
  }
}

// ---------------- k_gating: logits(f64) -> top2 -> gates; xb; out-init -------
__global__ __launch_bounds__(256) void k_gating(
    const float* __restrict__ x,      // [N][D]
    const float* __restrict__ wg,     // [D][E]
    const float* __restrict__ c,      // [E][OUT]
    unsigned short* __restrict__ xb,  // [N][D] bf16
    float* __restrict__ out,          // [N][OUT] (init with -bias correction)
    int* __restrict__ routeE,         // [N] packed e1 | e2<<8
    float* __restrict__ routeG) {     // [N][2]
  __shared__ double swg[DIM * NEXP];    // 16 KB
  __shared__ float  chunk[256 * 33];    // 33.8 KB (pad 33 -> conflict-free)
  __shared__ float  sG[256 * 2];
  __shared__ int    sE[256];
  int tid = threadIdx.x;
  int tok0 = blockIdx.x * 256;

  for (int i = tid; i < DIM * NEXP; i += 256) swg[i] = (double)wg[i];

  double p[NEXP];
  #pragma unroll
  for (int e = 0; e < NEXP; e++) p[e] = 0.0;

  for (int dc = 0; dc < 8; dc++) {      // 8 chunks of 32 dims
    __syncthreads();
    #pragma unroll
    for (int i = 0; i < 8; i++) {       // stage [256 tok][32 dim], coalesced
      int f = i * 256 + tid;
      int r = f >> 3, c4 = (f & 7) * 4;
      const float4 v = *(const float4*)(x + (size_t)(tok0 + r) * DIM + dc * 32 + c4);
      ushort4 h; h.x = f2bf(v.x); h.y = f2bf(v.y); h.z = f2bf(v.z); h.w = f2bf(v.w);
      *(ushort4*)(xb + (size_t)(tok0 + r) * DIM + dc * 32 + c4) = h;
      float* dst = &chunk[r * 33 + c4];
      dst[0] = v.x; dst[1] = v.y; dst[2] = v.z; dst[3] = v.w;
    }
    __syncthreads();
    #pragma unroll 8
    for (int cc = 0; cc < 32; cc++) {   // thread t owns token t
      double xv = (double)chunk[tid * 33 + cc];
      const double* wrow = &swg[(dc * 32 + cc) * NEXP];  // broadcast read
      #pragma unroll
      for (int e = 0; e < NEXP; e++) p[e] += xv * wrow[e];
    }
  }

  // top-2 (ties -> lowest index, matches jax.lax.top_k)
  int i1 = 0; double v1 = p[0];
  #pragma unroll
  for (int e = 1; e < NEXP; e++) { if (p[e] > v1) { v1 = p[e]; i1 = e; } }
  int i2 = -1; double v2 = -1e300;
  #pragma unroll
  for (int e = 0; e < NEXP; e++) { if (e != i1 && p[e] > v2) { v2 = p[e]; i2 = e; } }
  double t = exp(v2 - v1);
  float g1 = (float)(1.0 / (1.0 + t));
  float g2 = 1.0f - g1;

  int n = tok0 + tid;
  int epack = i1 | (i2 << 8);
  routeE[n] = epack;
  *(float2*)(routeG + 2 * (size_t)n) = make_float2(g1, g2);
  sE[tid] = epack; sG[tid * 2] = g1; sG[tid * 2 + 1] = g2;
  __syncthreads();

  // out init: -(g1*c[e1] + g2*c[e2]), wave-per-row coalesced
  int w = tid >> 6, lane = tid & 63;
  for (int it = 0; it < 64; it++) {
    int r = w * 64 + it;
    int ep = sE[r];
    int e1 = ep & 255, e2 = ep >> 8;
    float gg1 = sG[r * 2], gg2 = sG[r * 2 + 1];
    float4 c1 = *(const float4*)(c + e1 * 256 + lane * 4);
    float4 c2 = *(const float4*)(c + e2 * 256 + lane * 4);
    float4 o;
    o.x = -(gg1 * c1.x + gg2 * c2.x);
    o.y = -(gg1 * c1.y + gg2 * c2.y);
    o.z = -(gg1 * c1.z + gg2 * c2.z);
    o.w = -(gg1 * c1.w + gg2 * c2.w);
    *(float4*)(out + (size_t)(tok0 + r) * 256 + lane * 4) = o;
  }
}

// ---------------- k_route: build per-expert token lists ----------------------
__global__ __launch_bounds__(1024) void k_route(
    const int* __restrict__ routeE, const float* __restrict__ routeG,
    int* __restrict__ cursor, int* __restrict__ srcTok, float* __restrict__ srcGate) {
  __shared__ int cnt[NEXP], base[NEXP];
  int tid = threadIdx.x;
  if (tid < NEXP) cnt[tid] = 0;
  __syncthreads();
  int n = blockIdx.x * 1024 + tid;
  int ep = routeE[n];
  int e1 = ep & 255, e2 = ep >> 8;
  float2 g = *(const float2*)(routeG + 2 * (size_t)n);
  int r1 = atomicAdd(&cnt[e1], 1);
  int r2 = atomicAdd(&cnt[e2], 1);
  __syncthreads();
  if (tid < NEXP) base[tid] = atomicAdd(&cursor[tid], cnt[tid]);
  __syncthreads();
  int p1 = base[e1] + r1;
  srcTok[e1 * CAP + p1] = n; srcGate[e1 * CAP + p1] = g.x;
  int p2 = base[e2] + r2;
  srcTok[e2 * CAP + p2] = n; srcGate[e2 * CAP + p2] = g.y;
}

// ---------------- k_gemm: grouped GEMM, direct-from-L2 fragments -------------
// tile 128 rows x 128 cols, 4 waves (2x2), each wave 64x64 via 4x4 mfma tiles
__global__ __launch_bounds__(256) void k_gemm(
    const unsigned short* __restrict__ xb,
    const unsigned short* __restrict__ Wb,
    const int* __restrict__ cursor,
    const int* __restrict__ srcTok, const float* __restrict__ srcGate,
    float* __restrict__ out) {
  __shared__ int   sTok[128];
  __shared__ float sG[128];
  int tid = threadIdx.x;

  // map block -> (expert, m-tile, n-tile)
  int rem = blockIdx.x, e = 0, ne = 0;
  for (e = 0; e < NEXP; e++) {
    ne = cursor[e];
    int tiles = ((ne + 127) >> 7) * 2;
    if (rem < tiles) break;
    rem -= tiles;
  }
  if (e == NEXP) return;
  int mt = rem >> 1, nt = rem & 1;

  if (tid < 128) {
    int idx = mt * 128 + tid;
    bool v = idx < ne;
    sTok[tid] = v ? srcTok[e * CAP + idx] : 0;
    sG[tid]   = v ? srcGate[e * CAP + idx] : 0.f;   // pad rows: gate 0 => adds 0
  }
  __syncthreads();

  int w = tid >> 6, lane = tid & 63;
  int wm = w & 1, wn = w >> 1;
  int lr = lane & 15, lk = lane >> 4;   // frag row/col = lane&15, k-chunk = lane>>4

  const unsigned short* aBase[4];
  #pragma unroll
  for (int i = 0; i < 4; i++)
    aBase[i] = xb + (size_t)sTok[wm * 64 + i * 16 + lr] * DIM + lk * 8;
  const unsigned short* bBase[4];
  #pragma unroll
  for (int j = 0; j < 4; j++)
    bBase[j] = Wb + (size_t)e * 65536 + (size_t)(nt * 128 + wn * 64 + j * 16 + lr) * DIM + lk * 8;

  frag_cd acc[4][4];
  #pragma unroll
  for (int i = 0; i < 4; i++)
    #pragma unroll
    for (int j = 0; j < 4; j++)
      acc[i][j] = (frag_cd){0.f, 0.f, 0.f, 0.f};

  #pragma unroll
  for (int kk = 0; kk < 8; kk++) {      // K=256, 32 per step, no barriers
    frag_ab a[4], b[4];
    #pragma unroll
    for (int i = 0; i < 4; i++) a[i] = *(const frag_ab*)(aBase[i] + kk * 32);
    #pragma unroll
    for (int j = 0; j < 4; j++) b[j] = *(const frag_ab*)(bBase[j] + kk * 32);
    #pragma unroll
    for (int i = 0; i < 4; i++)
      #pragma unroll
      for (int j = 0; j < 4; j++)
        acc[i][j] = __builtin_amdgcn_mfma_f32_16x16x32_bf16(a[i], b[j], acc[i][j], 0, 0, 0);
  }

  // epilogue: C/D layout col=lane&15, row=(lane>>4)*4+reg  [m89-verified]
  #pragma unroll
  for (int i = 0; i < 4; i++) {
    #pragma unroll
    for (int rr = 0; rr < 4; rr++) {
      int m = wm * 64 + i * 16 + lk * 4 + rr;
      int tokn = sTok[m];
      float g = sG[m];
      float* orow = out + (size_t)tokn * 256;
      #pragma unroll
      for (int j = 0; j < 4; j++) {
        int colg = nt * 128 + wn * 64 + j * 16 + lr;
        atomicAdd(orow + colg, g * acc[i][j][rr]);
      }
    }
  }
}

extern "C" void kernel_launch(void* const* d_in, const int* in_sizes, int n_in,
                              void* d_out, int out_size, void* d_ws, size_t ws_size,
                              hipStream_t stream) {
  const float* x    = (const float*)d_in[0];  // [N][D]
  const float* wg   = (const float*)d_in[1];  // [D][E]
  const float* bias = (const float*)d_in[2];  // [E][D]
  const float* w    = (const float*)d_in[3];  // [E][OUT][D]
  float* out = (float*)d_out;
  char* ws = (char*)d_ws;

  unsigned short* xb = (unsigned short*)(ws);                 // 33,554,432 B
  unsigned short* Wb = (unsigned short*)(ws + 33554432);      //  1,048,576 B
  float* c           = (float*)(ws + 34603008);               //      8,192 B
  int* cursor        = (int*)(ws + 34611200);                 //         64 B
  int* routeE        = (int*)(ws + 34611264);                 //    262,144 B
  float* routeG      = (float*)(ws + 34873408);               //    524,288 B
  int* srcTok        = (int*)(ws + 35397696);                 //  2,097,152 B
  float* srcGate     = (float*)(ws + 37494848);               //  2,097,152 B  (total ~39.6 MB)

  hipLaunchKernelGGL(k_prep,   dim3(1024), dim3(256),  0, stream, w, bias, Wb, c, cursor);
  hipLaunchKernelGGL(k_gating, dim3(256),  dim3(256),  0, stream, x, wg, c, xb, out, routeE, routeG);
  hipLaunchKernelGGL(k_route,  dim3(64),   dim3(1024), 0, stream, routeE, routeG, cursor, srcTok, srcGate);
  hipLaunchKernelGGL(k_gemm,   dim3(2080), dim3(256),  0, stream, xb, Wb, cursor, srcTok, srcGate, out);
}

// Round 3
// 302.370 us; speedup vs baseline: 1.1152x; 1.1152x over previous
//
#include <hip/hip_runtime.h>
#include <hip/hip_bf16.h>
#include <math.h>

#define N_TOK 65536
#define DIM   256
#define NEXP  8

using frag_ab = __attribute__((ext_vector_type(8))) short;   // 8 bf16 (4 VGPRs)
using frag_cd = __attribute__((ext_vector_type(4))) float;   // 4 fp32 acc

__device__ __forceinline__ unsigned short f2bf(float f) {
  unsigned u = __float_as_uint(f);
  u += 0x7FFFu + ((u >> 16) & 1u);   // RNE
  return (unsigned short)(u >> 16);
}

// meta int layout in ws: [0:8)=counts1 [8:16)=counts2 [16:24)=base1
// [24:32)=base2 [32:40)=cursor1 [40:48)=cursor2

// ---- k_prep: Wb=bf16(W); c[e][o]=bias_e . W_e[o]; zero meta -----------------
__global__ __launch_bounds__(256) void k_prep(
    const float* __restrict__ w,      // expert_weight [E][OUT][D]
    const float* __restrict__ bias,   // expert_bias   [E][D]
    unsigned short* __restrict__ Wb,
    float* __restrict__ c,            // [E][OUT]
    int* __restrict__ meta) {
  int b = blockIdx.x, tid = threadIdx.x;
  if (b < 512) {
    int gid = b * 256 + tid;                  // 512*256*4 = 524288 floats
    float4 v = ((const float4*)w)[gid];
    ushort4 h; h.x = f2bf(v.x); h.y = f2bf(v.y); h.z = f2bf(v.z); h.w = f2bf(v.w);
    ((ushort4*)Wb)[gid] = h;
    if (b == 0 && tid < 48) meta[tid] = 0;
  } else {
    int wid = ((b - 512) * 256 + tid) >> 6;   // 0..2047 : one wave per (e,o)
    int lane = tid & 63;
    int e = wid >> 8, o = wid & 255;
    const float* br = bias + e * DIM + lane * 4;
    const float* wr = w + (size_t)(e * 256 + o) * DIM + lane * 4;
    float s = br[0] * wr[0] + br[1] * wr[1] + br[2] * wr[2] + br[3] * wr[3];
    #pragma unroll
    for (int m = 1; m < 64; m <<= 1) s += __shfl_xor(s, m, 64);
    if (lane == 0) c[e * 256 + o] = s;
  }
}

// ---- k_gating: logits(f64) -> top2 gates; xb cast; per-choice histograms ----
__global__ __launch_bounds__(256) void k_gating(
    const float* __restrict__ x,      // [N][D]
    const float* __restrict__ wg,     // [D][E]
    unsigned short* __restrict__ xb,  // [N][D] bf16
    int* __restrict__ routeE,         // [N] packed e1 | e2<<8
    float* __restrict__ routeG,       // [N][2]
    int* __restrict__ meta) {
  __shared__ double swg[DIM * NEXP];    // 16 KB
  __shared__ float  chunk[256 * 33];    // 33.8 KB (pad 33 -> conflict-free)
  __shared__ int    hcnt[2 * NEXP];
  int tid = threadIdx.x;
  int tok0 = blockIdx.x * 256;

  for (int i = tid; i < DIM * NEXP; i += 256) swg[i] = (double)wg[i];
  if (tid < 2 * NEXP) hcnt[tid] = 0;

  double p[NEXP];
  #pragma unroll
  for (int e = 0; e < NEXP; e++) p[e] = 0.0;

  for (int dc = 0; dc < 8; dc++) {      // 8 chunks of 32 dims
    __syncthreads();
    #pragma unroll
    for (int i = 0; i < 8; i++) {       // stage [256 tok][32 dim], coalesced
      int f = i * 256 + tid;
      int r = f >> 3, c4 = (f & 7) * 4;
      const float4 v = *(const float4*)(x + (size_t)(tok0 + r) * DIM + dc * 32 + c4);
      ushort4 h; h.x = f2bf(v.x); h.y = f2bf(v.y); h.z = f2bf(v.z); h.w = f2bf(v.w);
      *(ushort4*)(xb + (size_t)(tok0 + r) * DIM + dc * 32 + c4) = h;
      float* dst = &chunk[r * 33 + c4];
      dst[0] = v.x; dst[1] = v.y; dst[2] = v.z; dst[3] = v.w;
    }
    __syncthreads();
    #pragma unroll 8
    for (int cc = 0; cc < 32; cc++) {   // thread t owns token t
      double xv = (double)chunk[tid * 33 + cc];
      const double* wrow = &swg[(dc * 32 + cc) * NEXP];  // broadcast read
      #pragma unroll
      for (int e = 0; e < NEXP; e++) p[e] += xv * wrow[e];
    }
  }

  // top-2 (ties -> lowest index, matches jax.lax.top_k)
  int i1 = 0; double v1 = p[0];
  #pragma unroll
  for (int e = 1; e < NEXP; e++) { if (p[e] > v1) { v1 = p[e]; i1 = e; } }
  int i2 = -1; double v2 = -1e300;
  #pragma unroll
  for (int e = 0; e < NEXP; e++) { if (e != i1 && p[e] > v2) { v2 = p[e]; i2 = e; } }
  double t = exp(v2 - v1);
  float g1 = (float)(1.0 / (1.0 + t));
  float g2 = 1.0f - g1;

  int n = tok0 + tid;
  routeE[n] = i1 | (i2 << 8);
  *(float2*)(routeG + 2 * (size_t)n) = make_float2(g1, g2);
  atomicAdd(&hcnt[i1], 1);
  atomicAdd(&hcnt[NEXP + i2], 1);
  __syncthreads();
  if (tid < 2 * NEXP) atomicAdd(&meta[tid], hcnt[tid]);
}

// ---- k_scan: 128-aligned exclusive scans -> base1/2, cursor1/2 --------------
__global__ void k_scan(int* __restrict__ meta) {
  if (threadIdx.x == 0) {
    int run = 0;
    for (int e = 0; e < NEXP; e++) {
      meta[16 + e] = run; meta[32 + e] = run;          // base1, cursor1
      run += ((meta[e] + 127) >> 7) << 7;
    }
    run = 0;
    for (int e = 0; e < NEXP; e++) {
      meta[24 + e] = run; meta[40 + e] = run;          // base2, cursor2
      run += ((meta[8 + e] + 127) >> 7) << 7;
    }
  }
}

// ---- k_scatter: two expert-grouped permutations (first/second choice) -------
__global__ __launch_bounds__(1024) void k_scatter(
    const int* __restrict__ routeE, const float* __restrict__ routeG,
    int* __restrict__ meta,
    int* __restrict__ srcTok1, float* __restrict__ srcGate1,
    int* __restrict__ srcTok2, float* __restrict__ srcGate2) {
  __shared__ int cnt[2 * NEXP], bse[2 * NEXP];
  int tid = threadIdx.x;
  if (tid < 2 * NEXP) cnt[tid] = 0;
  __syncthreads();
  int n = blockIdx.x * 1024 + tid;
  int ep = routeE[n];
  int e1 = ep & 255, e2 = ep >> 8;
  float2 g = *(const float2*)(routeG + 2 * (size_t)n);
  int r1 = atomicAdd(&cnt[e1], 1);
  int r2 = atomicAdd(&cnt[NEXP + e2], 1);
  __syncthreads();
  if (tid < NEXP)            bse[tid] = atomicAdd(&meta[32 + tid], cnt[tid]);
  else if (tid < 2 * NEXP)   bse[tid] = atomicAdd(&meta[40 + (tid - NEXP)], cnt[tid]);
  __syncthreads();
  int p1 = bse[e1] + r1;
  srcTok1[p1] = n; srcGate1[p1] = g.x;
  int p2 = bse[NEXP + e2] + r2;
  srcTok2[p2] = n; srcGate2[p2] = g.y;
}

// ---- k_gemm: grouped GEMM, L2-fed fragments -------------------------------
// mode 0: out[n] = g*(acc - c[e]); mode 1: out[n] += g*(acc - c[e])
// tile 128 slots x 128 cols, 4 waves (2x2), each wave 64x64 via 4x4 mfma tiles
__global__ __launch_bounds__(256) void k_gemm(
    const unsigned short* __restrict__ xb,
    const unsigned short* __restrict__ Wb,
    const int* __restrict__ counts, const int* __restrict__ base,
    const int* __restrict__ srcTok, const float* __restrict__ srcGate,
    const float* __restrict__ c,
    float* __restrict__ out, int mode) {
  __shared__ int   sTok[128];
  __shared__ float sG[128];
  __shared__ float sCor[256];
  int tid = threadIdx.x;

  // map block -> (expert, m-tile, n-tile)
  int rem = blockIdx.x, e = 0, ne = 0;
  for (e = 0; e < NEXP; e++) {
    ne = counts[e];
    int tiles = ((ne + 127) >> 7) * 2;
    if (rem < tiles) break;
    rem -= tiles;
  }
  if (e == NEXP) return;
  int mt = rem >> 1, nt = rem & 1;
  int slot0 = base[e] + mt * 128;

  if (tid < 128) {
    int idx = mt * 128 + tid;
    bool v = idx < ne;
    sTok[tid] = v ? srcTok[slot0 + tid] : 0;
    sG[tid]   = v ? srcGate[slot0 + tid] : 0.f;
  } else if (tid < 192) {
    int t = tid - 128;
    ((float4*)sCor)[t] = ((const float4*)(c + e * 256))[t];
  }
  __syncthreads();

  int w = tid >> 6, lane = tid & 63;
  int wm = w & 1, wn = w >> 1;
  int lr = lane & 15, lk = lane >> 4;

  const unsigned short* aBase[4];
  #pragma unroll
  for (int i = 0; i < 4; i++)
    aBase[i] = xb + (size_t)sTok[wm * 64 + i * 16 + lr] * DIM + lk * 8;
  const unsigned short* bBase[4];
  #pragma unroll
  for (int j = 0; j < 4; j++)
    bBase[j] = Wb + (size_t)e * 65536 + (size_t)(nt * 128 + wn * 64 + j * 16 + lr) * DIM + lk * 8;

  frag_cd acc[4][4];
  #pragma unroll
  for (int i = 0; i < 4; i++)
    #pragma unroll
    for (int j = 0; j < 4; j++)
      acc[i][j] = (frag_cd){0.f, 0.f, 0.f, 0.f};

  // 2-deep register pipeline: loads for step kk+1 issued before MFMAs of kk
  frag_ab a[2][4], b[2][4];
  #pragma unroll
  for (int i = 0; i < 4; i++) a[0][i] = *(const frag_ab*)(aBase[i]);
  #pragma unroll
  for (int j = 0; j < 4; j++) b[0][j] = *(const frag_ab*)(bBase[j]);

  #pragma unroll
  for (int kk = 0; kk < 8; kk++) {      // K=256, 32 per step, no barriers
    int cur = kk & 1, nxt = cur ^ 1;
    if (kk < 7) {
      #pragma unroll
      for (int i = 0; i < 4; i++) a[nxt][i] = *(const frag_ab*)(aBase[i] + (kk + 1) * 32);
      #pragma unroll
      for (int j = 0; j < 4; j++) b[nxt][j] = *(const frag_ab*)(bBase[j] + (kk + 1) * 32);
    }
    #pragma unroll
    for (int i = 0; i < 4; i++)
      #pragma unroll
      for (int j = 0; j < 4; j++)
        acc[i][j] = __builtin_amdgcn_mfma_f32_16x16x32_bf16(a[cur][i], b[cur][j], acc[i][j], 0, 0, 0);
  }

  // epilogue: C/D layout col=lane&15, row=(lane>>4)*4+reg  [m89-verified]
  int colbase = nt * 128 + wn * 64;
  #pragma unroll
  for (int i = 0; i < 4; i++) {
    #pragma unroll
    for (int rr = 0; rr < 4; rr++) {
      int m = wm * 64 + i * 16 + lk * 4 + rr;
      if (mt * 128 + m < ne) {          // pad rows: no store (don't clobber tok 0)
        int tokn = sTok[m];
        float g = sG[m];
        float* orow = out + (size_t)tokn * 256 + colbase;
        #pragma unroll
        for (int j = 0; j < 4; j++) {
          int col = j * 16 + lr;
          float v = g * (acc[i][j][rr] - sCor[colbase + col]);
          if (mode) v += orow[col];
          orow[col] = v;
        }
      }
    }
  }
}

extern "C" void kernel_launch(void* const* d_in, const int* in_sizes, int n_in,
                              void* d_out, int out_size, void* d_ws, size_t ws_size,
                              hipStream_t stream) {
  const float* x    = (const float*)d_in[0];  // [N][D]
  const float* wg   = (const float*)d_in[1];  // [D][E]
  const float* bias = (const float*)d_in[2];  // [E][D]
  const float* w    = (const float*)d_in[3];  // [E][OUT][D]
  float* out = (float*)d_out;
  char* ws = (char*)d_ws;

  // total ws usage: ~36.5 MB (round-1 proved >=39.6 MB available)
  unsigned short* xb = (unsigned short*)(ws);                 // 33,554,432 B
  unsigned short* Wb = (unsigned short*)(ws + 33554432);      //  1,048,576 B
  float* c           = (float*)(ws + 34603008);               //      8,192 B
  int* meta          = (int*)(ws + 34611200);                 //        256 B
  int* routeE        = (int*)(ws + 34611456);                 //    262,144 B
  float* routeG      = (float*)(ws + 34873600);               //    524,288 B
  int* srcTok1       = (int*)(ws + 35397888);                 //    266,240 B (66560 slots)
  float* srcGate1    = (float*)(ws + 35664128);               //    266,240 B
  int* srcTok2       = (int*)(ws + 35930368);                 //    266,240 B
  float* srcGate2    = (float*)(ws + 36196608);               //    266,240 B -> ends 36,462,848

  hipLaunchKernelGGL(k_prep,    dim3(1024), dim3(256),  0, stream, w, bias, Wb, c, meta);
  hipLaunchKernelGGL(k_gating,  dim3(256),  dim3(256),  0, stream, x, wg, xb, routeE, routeG, meta);
  hipLaunchKernelGGL(k_scan,    dim3(1),    dim3(64),   0, stream, meta);
  hipLaunchKernelGGL(k_scatter, dim3(64),   dim3(1024), 0, stream, routeE, routeG, meta,
                     srcTok1, srcGate1, srcTok2, srcGate2);
  hipLaunchKernelGGL(k_gemm,    dim3(1040), dim3(256),  0, stream, xb, Wb,
                     meta,     meta + 16, srcTok1, srcGate1, c, out, 0);
  hipLaunchKernelGGL(k_gemm,    dim3(1040), dim3(256),  0, stream, xb, Wb,
                     meta + 8, meta + 24, srcTok2, srcGate2, c, out, 1);
}

// Round 4
// 231.422 us; speedup vs baseline: 1.4571x; 1.3066x over previous
//
#include <hip/hip_runtime.h>
#include <hip/hip_bf16.h>
#include <math.h>

#define N_TOK 65536
#define DIM   256
#define NEXP  8

using frag_ab = __attribute__((ext_vector_type(8))) short;   // 8 bf16 (4 VGPRs)
using frag_cd = __attribute__((ext_vector_type(4))) float;   // 4 fp32 acc

__device__ __forceinline__ unsigned short f2bf(float f) {
  unsigned u = __float_as_uint(f);
  u += 0x7FFFu + ((u >> 16) & 1u);   // RNE
  return (unsigned short)(u >> 16);
}

// meta int layout in ws: [0:8)=counts1 [8:16)=counts2 [16:24)=base1
// [24:32)=base2 [32:40)=cursor1 [40:48)=cursor2

// ---- k_prep: Wb_t = bf16(W) pre-tiled [e][kk][256][32]; c[e][o]=bias_e.W_e[o]
__global__ __launch_bounds__(256) void k_prep(
    const float* __restrict__ w,      // expert_weight [E][OUT][D]
    const float* __restrict__ bias,   // expert_bias   [E][D]
    unsigned short* __restrict__ Wb,  // tiled: [(e*8+kk)*256 + r]*32 + q
    float* __restrict__ c,            // [E][OUT]
    int* __restrict__ meta) {
  int b = blockIdx.x, tid = threadIdx.x;
  if (b < 512) {
    int gid = b * 256 + tid;                  // 131072 threads x 4 floats
    int f = gid * 4;
    float4 v = ((const float4*)w)[gid];
    ushort4 h; h.x = f2bf(v.x); h.y = f2bf(v.y); h.z = f2bf(v.z); h.w = f2bf(v.w);
    int e = f >> 16, r = (f >> 8) & 255, d = f & 255;
    int kk = d >> 5, q = d & 31;
    *(ushort4*)(Wb + ((size_t)(e * 8 + kk) * 256 + r) * 32 + q) = h;
    if (b == 0 && tid < 48) meta[tid] = 0;
  } else {
    int wid = ((b - 512) * 256 + tid) >> 6;   // 0..2047 : one wave per (e,o)
    int lane = tid & 63;
    int e = wid >> 8, o = wid & 255;
    const float* br = bias + e * DIM + lane * 4;
    const float* wr = w + (size_t)(e * 256 + o) * DIM + lane * 4;
    float s = br[0] * wr[0] + br[1] * wr[1] + br[2] * wr[2] + br[3] * wr[3];
    #pragma unroll
    for (int m = 1; m < 64; m <<= 1) s += __shfl_xor(s, m, 64);
    if (lane == 0) c[e * 256 + o] = s;
  }
}

// ---- k_gating: logits(f64) -> top2 gates; xb cast; per-choice histograms ----
__global__ __launch_bounds__(256) void k_gating(
    const float* __restrict__ x,      // [N][D]
    const float* __restrict__ wg,     // [D][E]
    unsigned short* __restrict__ xb,  // [N][D] bf16
    int* __restrict__ routeE,         // [N] packed e1 | e2<<8
    float* __restrict__ routeG,       // [N][2]
    int* __restrict__ meta) {
  __shared__ double swg[DIM * NEXP];    // 16 KB
  __shared__ float  chunk[256 * 33];    // 33.8 KB (pad 33 -> conflict-free)
  __shared__ int    hcnt[2 * NEXP];
  int tid = threadIdx.x;
  int tok0 = blockIdx.x * 256;

  for (int i = tid; i < DIM * NEXP; i += 256) swg[i] = (double)wg[i];
  if (tid < 2 * NEXP) hcnt[tid] = 0;

  double p[NEXP];
  #pragma unroll
  for (int e = 0; e < NEXP; e++) p[e] = 0.0;

  for (int dc = 0; dc < 8; dc++) {      // 8 chunks of 32 dims
    __syncthreads();
    #pragma unroll
    for (int i = 0; i < 8; i++) {       // stage [256 tok][32 dim], coalesced
      int f = i * 256 + tid;
      int r = f >> 3, c4 = (f & 7) * 4;
      const float4 v = *(const float4*)(x + (size_t)(tok0 + r) * DIM + dc * 32 + c4);
      ushort4 h; h.x = f2bf(v.x); h.y = f2bf(v.y); h.z = f2bf(v.z); h.w = f2bf(v.w);
      *(ushort4*)(xb + (size_t)(tok0 + r) * DIM + dc * 32 + c4) = h;
      float* dst = &chunk[r * 33 + c4];
      dst[0] = v.x; dst[1] = v.y; dst[2] = v.z; dst[3] = v.w;
    }
    __syncthreads();
    #pragma unroll 8
    for (int cc = 0; cc < 32; cc++) {   // thread t owns token t
      double xv = (double)chunk[tid * 33 + cc];
      const double* wrow = &swg[(dc * 32 + cc) * NEXP];  // broadcast read
      #pragma unroll
      for (int e = 0; e < NEXP; e++) p[e] += xv * wrow[e];
    }
  }

  // top-2 (ties -> lowest index, matches jax.lax.top_k)
  int i1 = 0; double v1 = p[0];
  #pragma unroll
  for (int e = 1; e < NEXP; e++) { if (p[e] > v1) { v1 = p[e]; i1 = e; } }
  int i2 = -1; double v2 = -1e300;
  #pragma unroll
  for (int e = 0; e < NEXP; e++) { if (e != i1 && p[e] > v2) { v2 = p[e]; i2 = e; } }
  double t = exp(v2 - v1);
  float g1 = (float)(1.0 / (1.0 + t));
  float g2 = 1.0f - g1;

  int n = tok0 + tid;
  routeE[n] = i1 | (i2 << 8);
  *(float2*)(routeG + 2 * (size_t)n) = make_float2(g1, g2);
  atomicAdd(&hcnt[i1], 1);
  atomicAdd(&hcnt[NEXP + i2], 1);
  __syncthreads();
  if (tid < 2 * NEXP) atomicAdd(&meta[tid], hcnt[tid]);
}

// ---- k_scan: 128-aligned exclusive scans -> base1/2, cursor1/2 --------------
__global__ void k_scan(int* __restrict__ meta) {
  if (threadIdx.x == 0) {
    int run = 0;
    for (int e = 0; e < NEXP; e++) {
      meta[16 + e] = run; meta[32 + e] = run;          // base1, cursor1
      run += ((meta[e] + 127) >> 7) << 7;
    }
    run = 0;
    for (int e = 0; e < NEXP; e++) {
      meta[24 + e] = run; meta[40 + e] = run;          // base2, cursor2
      run += ((meta[8 + e] + 127) >> 7) << 7;
    }
  }
}

// ---- k_scatter: two expert-grouped permutations (first/second choice) -------
__global__ __launch_bounds__(1024) void k_scatter(
    const int* __restrict__ routeE, const float* __restrict__ routeG,
    int* __restrict__ meta,
    int* __restrict__ srcTok1, float* __restrict__ srcGate1,
    int* __restrict__ srcTok2, float* __restrict__ srcGate2) {
  __shared__ int cnt[2 * NEXP], bse[2 * NEXP];
  int tid = threadIdx.x;
  if (tid < 2 * NEXP) cnt[tid] = 0;
  __syncthreads();
  int n = blockIdx.x * 1024 + tid;
  int ep = routeE[n];
  int e1 = ep & 255, e2 = ep >> 8;
  float2 g = *(const float2*)(routeG + 2 * (size_t)n);
  int r1 = atomicAdd(&cnt[e1], 1);
  int r2 = atomicAdd(&cnt[NEXP + e2], 1);
  __syncthreads();
  if (tid < NEXP)            bse[tid] = atomicAdd(&meta[32 + tid], cnt[tid]);
  else if (tid < 2 * NEXP)   bse[tid] = atomicAdd(&meta[40 + (tid - NEXP)], cnt[tid]);
  __syncthreads();
  int p1 = bse[e1] + r1;
  srcTok1[p1] = n; srcGate1[p1] = g.x;
  int p2 = bse[NEXP + e2] + r2;
  srcTok2[p2] = n; srcGate2[p2] = g.y;
}

// ---- k_gemm: LDS-staged grouped GEMM, BM=128 BN=256 BK=32, 512 thr / 8 waves
// LDS swizzle: 16B chunk p of row r lives at position (p+r)&3  -> conflict-free
// mode 0: out[n] = g*(acc - c[e]); mode 1: out[n] += g*(acc - c[e])
__global__ __launch_bounds__(512, 4) void k_gemm(
    const unsigned short* __restrict__ xb,
    const unsigned short* __restrict__ Wb,   // tiled [e][kk][256][32]
    const int* __restrict__ counts, const int* __restrict__ base,
    const int* __restrict__ srcTok, const float* __restrict__ srcGate,
    const float* __restrict__ c,
    float* __restrict__ out, int mode) {
  __shared__ unsigned short sA[128 * 32];   //  8 KB
  __shared__ unsigned short sB[256 * 32];   // 16 KB
  __shared__ int   sTok[128];
  __shared__ float sG[128];
  __shared__ float sCor[256];
  int tid = threadIdx.x;

  // map block -> (expert, m-tile)
  int rem = blockIdx.x, e = 0, ne = 0;
  for (e = 0; e < NEXP; e++) {
    ne = counts[e];
    int tiles = (ne + 127) >> 7;
    if (rem < tiles) break;
    rem -= tiles;
  }
  if (e == NEXP) return;
  int mt = rem;
  int slot0 = base[e] + mt * 128;

  if (tid < 128) {
    int idx = mt * 128 + tid;
    bool v = idx < ne;
    sTok[tid] = v ? srcTok[slot0 + tid] : 0;
    sG[tid]   = v ? srcGate[slot0 + tid] : 0.f;
  } else if (tid < 192) {
    int t = tid - 128;
    ((float4*)sCor)[t] = ((const float4*)(c + e * 256))[t];
  }
  __syncthreads();

  // staging geometry: thread t -> A chunk (r=t>>2, p=t&3); B chunks t, t+512
  int sr = tid >> 2, sp = tid & 3;
  const unsigned short* aSrc = xb + (size_t)sTok[sr] * 256 + sp * 8;
  const unsigned short* bTile = Wb + (size_t)e * 8 * 8192;   // + kk*8192
  int wA  = sr * 32 + ((sp + sr) & 3) * 8;
  int wB0 = sr * 32 + ((sp + sr) & 3) * 8;                   // rows 0..127
  int rB1 = 128 + sr;
  int wB1 = rB1 * 32 + ((sp + rB1) & 3) * 8;                 // rows 128..255

  // fragment geometry (constant across kk): gc = lk, pos = (lk + row) & 3
  int w = tid >> 6, lane = tid & 63;
  int wm = w & 1, wn = w >> 1;                                // wm 0..1, wn 0..3
  int lr = lane & 15, lk = lane >> 4;
  int offA[4], offB[4];
  #pragma unroll
  for (int i = 0; i < 4; i++) {
    int ra = wm * 64 + i * 16 + lr;
    offA[i] = ra * 32 + ((lk + ra) & 3) * 8;
    int rb = wn * 64 + i * 16 + lr;
    offB[i] = rb * 32 + ((lk + rb) & 3) * 8;
  }

  frag_cd acc[4][4];
  #pragma unroll
  for (int i = 0; i < 4; i++)
    #pragma unroll
    for (int j = 0; j < 4; j++)
      acc[i][j] = (frag_cd){0.f, 0.f, 0.f, 0.f};

  uint4 ra4 = *(const uint4*)(aSrc);
  uint4 rb4a = *(const uint4*)(bTile + tid * 8);
  uint4 rb4b = *(const uint4*)(bTile + (tid + 512) * 8);

  for (int kk = 0; kk < 8; kk++) {
    __syncthreads();                       // prev iter's LDS reads done
    *(uint4*)(sA + wA)  = ra4;
    *(uint4*)(sB + wB0) = rb4a;
    *(uint4*)(sB + wB1) = rb4b;
    __syncthreads();
    if (kk < 7) {                          // prefetch next tile during MFMAs
      ra4  = *(const uint4*)(aSrc + (kk + 1) * 32);
      const unsigned short* bt = bTile + (size_t)(kk + 1) * 8192;
      rb4a = *(const uint4*)(bt + tid * 8);
      rb4b = *(const uint4*)(bt + (tid + 512) * 8);
    }
    frag_ab a[4], b[4];
    #pragma unroll
    for (int i = 0; i < 4; i++) a[i] = *(const frag_ab*)(sA + offA[i]);
    #pragma unroll
    for (int j = 0; j < 4; j++) b[j] = *(const frag_ab*)(sB + offB[j]);
    #pragma unroll
    for (int i = 0; i < 4; i++)
      #pragma unroll
      for (int j = 0; j < 4; j++)
        acc[i][j] = __builtin_amdgcn_mfma_f32_16x16x32_bf16(a[i], b[j], acc[i][j], 0, 0, 0);
  }

  // epilogue: C/D layout col=lane&15, row=(lane>>4)*4+reg  [m89-verified]
  #pragma unroll
  for (int i = 0; i < 4; i++) {
    #pragma unroll
    for (int rr = 0; rr < 4; rr++) {
      int m = wm * 64 + i * 16 + lk * 4 + rr;
      if (mt * 128 + m < ne) {             // pad rows: no store
        int tokn = sTok[m];
        float g = sG[m];
        float* orow = out + (size_t)tokn * 256;
        #pragma unroll
        for (int j = 0; j < 4; j++) {
          int col = wn * 64 + j * 16 + lr;
          float v = g * (acc[i][j][rr] - sCor[col]);
          if (mode) v += orow[col];
          orow[col] = v;
        }
      }
    }
  }
}

extern "C" void kernel_launch(void* const* d_in, const int* in_sizes, int n_in,
                              void* d_out, int out_size, void* d_ws, size_t ws_size,
                              hipStream_t stream) {
  const float* x    = (const float*)d_in[0];  // [N][D]
  const float* wg   = (const float*)d_in[1];  // [D][E]
  const float* bias = (const float*)d_in[2];  // [E][D]
  const float* w    = (const float*)d_in[3];  // [E][OUT][D]
  float* out = (float*)d_out;
  char* ws = (char*)d_ws;

  // total ws usage: ~36.5 MB (round-1 proved >=39.6 MB available)
  unsigned short* xb = (unsigned short*)(ws);                 // 33,554,432 B
  unsigned short* Wb = (unsigned short*)(ws + 33554432);      //  1,048,576 B (tiled)
  float* c           = (float*)(ws + 34603008);               //      8,192 B
  int* meta          = (int*)(ws + 34611200);                 //        256 B
  int* routeE        = (int*)(ws + 34611456);                 //    262,144 B
  float* routeG      = (float*)(ws + 34873600);               //    524,288 B
  int* srcTok1       = (int*)(ws + 35397888);                 //    266,240 B (66560 slots)
  float* srcGate1    = (float*)(ws + 35664128);               //    266,240 B
  int* srcTok2       = (int*)(ws + 35930368);                 //    266,240 B
  float* srcGate2    = (float*)(ws + 36196608);               //    266,240 B -> ends 36,462,848

  hipLaunchKernelGGL(k_prep,    dim3(1024), dim3(256),  0, stream, w, bias, Wb, c, meta);
  hipLaunchKernelGGL(k_gating,  dim3(256),  dim3(256),  0, stream, x, wg, xb, routeE, routeG, meta);
  hipLaunchKernelGGL(k_scan,    dim3(1),    dim3(64),   0, stream, meta);
  hipLaunchKernelGGL(k_scatter, dim3(64),   dim3(1024), 0, stream, routeE, routeG, meta,
                     srcTok1, srcGate1, srcTok2, srcGate2);
  hipLaunchKernelGGL(k_gemm,    dim3(520),  dim3(512),  0, stream, xb, Wb,
                     meta,     meta + 16, srcTok1, srcGate1, c, out, 0);
  hipLaunchKernelGGL(k_gemm,    dim3(520),  dim3(512),  0, stream, xb, Wb,
                     meta + 8, meta + 24, srcTok2, srcGate2, c, out, 1);
}

// Round 5
// 226.741 us; speedup vs baseline: 1.4871x; 1.0206x over previous
//
#include <hip/hip_runtime.h>
#include <hip/hip_bf16.h>
#include <math.h>

#define N_TOK 65536
#define DIM   256
#define NEXP  8

using frag_ab = __attribute__((ext_vector_type(8))) short;   // 8 bf16 (4 VGPRs)
using frag_cd = __attribute__((ext_vector_type(4))) float;   // 4 fp32 acc

__device__ __forceinline__ unsigned short f2bf(float f) {
  unsigned u = __float_as_uint(f);
  u += 0x7FFFu + ((u >> 16) & 1u);   // RNE
  return (unsigned short)(u >> 16);
}

// async 16B global->LDS: lds base is wave-uniform; lane i lands at base+i*16
__device__ __forceinline__ void gl2lds16(const unsigned short* g, unsigned short* l) {
  __builtin_amdgcn_global_load_lds(
      (const __attribute__((address_space(1))) void*)g,
      (__attribute__((address_space(3))) void*)l, 16, 0, 0);
}

// meta int layout in ws: [0:8)=counts1 [8:16)=counts2 [16:24)=base1
// [24:32)=base2 [32:40)=cursor1 [40:48)=cursor2

// ---- k_prep: Wb = bf16(W) [e][o][d]; c[e][o]=bias_e . W_e[o]; zero meta -----
__global__ __launch_bounds__(256) void k_prep(
    const float* __restrict__ w,      // expert_weight [E][OUT][D]
    const float* __restrict__ bias,   // expert_bias   [E][D]
    unsigned short* __restrict__ Wb,
    float* __restrict__ c,            // [E][OUT]
    int* __restrict__ meta) {
  int b = blockIdx.x, tid = threadIdx.x;
  if (b < 512) {
    int gid = b * 256 + tid;                  // 512*256*4 = 524288 floats
    float4 v = ((const float4*)w)[gid];
    ushort4 h; h.x = f2bf(v.x); h.y = f2bf(v.y); h.z = f2bf(v.z); h.w = f2bf(v.w);
    ((ushort4*)Wb)[gid] = h;
    if (b == 0 && tid < 48) meta[tid] = 0;
  } else {
    int wid = ((b - 512) * 256 + tid) >> 6;   // 0..2047 : one wave per (e,o)
    int lane = tid & 63;
    int e = wid >> 8, o = wid & 255;
    const float* br = bias + e * DIM + lane * 4;
    const float* wr = w + (size_t)(e * 256 + o) * DIM + lane * 4;
    float s = br[0] * wr[0] + br[1] * wr[1] + br[2] * wr[2] + br[3] * wr[3];
    #pragma unroll
    for (int m = 1; m < 64; m <<= 1) s += __shfl_xor(s, m, 64);
    if (lane == 0) c[e * 256 + o] = s;
  }
}

// ---- k_gating: 128 tok/block, 2 threads per token (dim split), f64 ranking --
__global__ __launch_bounds__(256) void k_gating(
    const float* __restrict__ x,      // [N][D]
    const float* __restrict__ wg,     // [D][E]
    unsigned short* __restrict__ xb,  // [N][D] bf16
    int* __restrict__ routeE,         // [N] packed e1 | e2<<8
    float* __restrict__ routeG,       // [N][2]
    int* __restrict__ meta) {
  __shared__ double swg[DIM * NEXP];    // 16 KB
  __shared__ float  chunk[128 * 33];    // 16.9 KB (pad 33 -> conflict-free)
  __shared__ double sPar[128 * NEXP];   // 8 KB
  __shared__ int    hcnt[2 * NEXP];
  int tid = threadIdx.x;
  int tok0 = blockIdx.x * 128;
  int sub = tid >> 7, tk = tid & 127;

  for (int i = tid; i < DIM * NEXP; i += 256) swg[i] = (double)wg[i];
  if (tid < 2 * NEXP) hcnt[tid] = 0;

  double p[NEXP];
  #pragma unroll
  for (int e = 0; e < NEXP; e++) p[e] = 0.0;

  for (int dc = 0; dc < 8; dc++) {      // 8 chunks of 32 dims
    __syncthreads();
    #pragma unroll
    for (int i = 0; i < 4; i++) {       // stage [128 tok][32 dim], coalesced
      int f = i * 256 + tid;
      int r = f >> 3, c4 = (f & 7) * 4;
      const float4 v = *(const float4*)(x + (size_t)(tok0 + r) * DIM + dc * 32 + c4);
      ushort4 h; h.x = f2bf(v.x); h.y = f2bf(v.y); h.z = f2bf(v.z); h.w = f2bf(v.w);
      *(ushort4*)(xb + (size_t)(tok0 + r) * DIM + dc * 32 + c4) = h;
      float* dst = &chunk[r * 33 + c4];
      dst[0] = v.x; dst[1] = v.y; dst[2] = v.z; dst[3] = v.w;
    }
    __syncthreads();
    if ((dc >> 2) == sub) {             // this thread's half of the dims
      #pragma unroll 8
      for (int cc = 0; cc < 32; cc++) {
        double xv = (double)chunk[tk * 33 + cc];
        const double* wrow = &swg[(dc * 32 + cc) * NEXP];  // broadcast read
        #pragma unroll
        for (int e = 0; e < NEXP; e++) p[e] += xv * wrow[e];
      }
    }
  }

  if (sub == 1) {
    #pragma unroll
    for (int e = 0; e < NEXP; e++) sPar[tk * NEXP + e] = p[e];
  }
  __syncthreads();
  if (sub == 0) {
    #pragma unroll
    for (int e = 0; e < NEXP; e++) p[e] += sPar[tk * NEXP + e];

    // top-2 (ties -> lowest index, matches jax.lax.top_k)
    int i1 = 0; double v1 = p[0];
    #pragma unroll
    for (int e = 1; e < NEXP; e++) { if (p[e] > v1) { v1 = p[e]; i1 = e; } }
    int i2 = -1; double v2 = -1e300;
    #pragma unroll
    for (int e = 0; e < NEXP; e++) { if (e != i1 && p[e] > v2) { v2 = p[e]; i2 = e; } }
    double t = exp(v2 - v1);
    float g1 = (float)(1.0 / (1.0 + t));
    float g2 = 1.0f - g1;

    int n = tok0 + tk;
    routeE[n] = i1 | (i2 << 8);
    *(float2*)(routeG + 2 * (size_t)n) = make_float2(g1, g2);
    atomicAdd(&hcnt[i1], 1);
    atomicAdd(&hcnt[NEXP + i2], 1);
  }
  __syncthreads();
  if (tid < 2 * NEXP) atomicAdd(&meta[tid], hcnt[tid]);
}

// ---- k_scan: 128-aligned exclusive scans -> base1/2, cursor1/2 --------------
__global__ void k_scan(int* __restrict__ meta) {
  if (threadIdx.x == 0) {
    int run = 0;
    for (int e = 0; e < NEXP; e++) {
      meta[16 + e] = run; meta[32 + e] = run;          // base1, cursor1
      run += ((meta[e] + 127) >> 7) << 7;
    }
    run = 0;
    for (int e = 0; e < NEXP; e++) {
      meta[24 + e] = run; meta[40 + e] = run;          // base2, cursor2
      run += ((meta[8 + e] + 127) >> 7) << 7;
    }
  }
}

// ---- k_scatter: two expert-grouped permutations (first/second choice) -------
__global__ __launch_bounds__(1024) void k_scatter(
    const int* __restrict__ routeE, const float* __restrict__ routeG,
    int* __restrict__ meta,
    int* __restrict__ srcTok1, float* __restrict__ srcGate1,
    int* __restrict__ srcTok2, float* __restrict__ srcGate2) {
  __shared__ int cnt[2 * NEXP], bse[2 * NEXP];
  int tid = threadIdx.x;
  if (tid < 2 * NEXP) cnt[tid] = 0;
  __syncthreads();
  int n = blockIdx.x * 1024 + tid;
  int ep = routeE[n];
  int e1 = ep & 255, e2 = ep >> 8;
  float2 g = *(const float2*)(routeG + 2 * (size_t)n);
  int r1 = atomicAdd(&cnt[e1], 1);
  int r2 = atomicAdd(&cnt[NEXP + e2], 1);
  __syncthreads();
  if (tid < NEXP)            bse[tid] = atomicAdd(&meta[32 + tid], cnt[tid]);
  else if (tid < 2 * NEXP)   bse[tid] = atomicAdd(&meta[40 + (tid - NEXP)], cnt[tid]);
  __syncthreads();
  int p1 = bse[e1] + r1;
  srcTok1[p1] = n; srcGate1[p1] = g.x;
  int p2 = bse[NEXP + e2] + r2;
  srcTok2[p2] = n; srcGate2[p2] = g.y;
}

// ---- k_gemm: m97-shape grouped GEMM. BM=BN=128, BK=64, 256 thr / 4 waves ----
// global_load_lds(16B) staging; source-side XOR swizzle: chunk c of row r
// lives at LDS pos (c+r)&7 (8 x 16B chunks per 64-col row) -> conflict-free.
// mode 0: out[n] = g*(acc - c[e]); mode 1: out[n] += g*(acc - c[e])
__global__ __launch_bounds__(256, 3) void k_gemm(
    const unsigned short* __restrict__ xb,
    const unsigned short* __restrict__ Wb,   // [e][o][d]
    const int* __restrict__ counts, const int* __restrict__ base,
    const int* __restrict__ srcTok, const float* __restrict__ srcGate,
    const float* __restrict__ c,
    float* __restrict__ out, int mode) {
  __shared__ unsigned short sA[128 * 64];   // 16 KB
  __shared__ unsigned short sB[128 * 64];   // 16 KB
  __shared__ int   sTok[128];
  __shared__ float sG[128];
  __shared__ float sCor[128];
  int tid = threadIdx.x;

  // map block -> (expert, m-tile, n-tile)
  int rem = blockIdx.x, e = 0, ne = 0;
  for (e = 0; e < NEXP; e++) {
    ne = counts[e];
    int tiles = ((ne + 127) >> 7) * 2;
    if (rem < tiles) break;
    rem -= tiles;
  }
  if (e == NEXP) return;
  int mt = rem >> 1, nt = rem & 1;
  int slot0 = base[e] + mt * 128;

  if (tid < 128) {
    int idx = mt * 128 + tid;
    bool v = idx < ne;
    sTok[tid] = v ? srcTok[slot0 + tid] : 0;
    sG[tid]   = v ? srcGate[slot0 + tid] : 0.f;
  } else if (tid < 160) {
    ((float4*)sCor)[tid - 128] = ((const float4*)(c + e * 256 + nt * 128))[tid - 128];
  }
  __syncthreads();

  int w = tid >> 6, lane = tid & 63;
  int lrow = lane >> 3, lchk = lane & 7;

  // staging addresses: wave w stages rows w*32..w*32+31, 4 groups of 8 rows
  const unsigned short* aSrc[4];
  const unsigned short* bSrc[4];
  unsigned short* aDst[4];
  unsigned short* bDst[4];
  #pragma unroll
  for (int q = 0; q < 4; q++) {
    int r0 = w * 32 + q * 8;
    int r  = r0 + lrow;                      // LDS-local row 0..127
    int cc = (lchk - r) & 7;                 // global chunk for this lane's pos
    aSrc[q] = xb + (size_t)sTok[r] * 256 + cc * 8;
    bSrc[q] = Wb + (size_t)e * 65536 + (size_t)(nt * 128 + r) * 256 + cc * 8;
    aDst[q] = sA + r0 * 64;
    bDst[q] = sB + r0 * 64;
  }

  // fragment read offsets: row ra, k-chunk c=ks*4+lk -> pos (c+ra)&7
  int wm = w & 1, wn = w >> 1;
  int lr = lane & 15, lk = lane >> 4;
  int offA[2][4], offB[2][4];
  #pragma unroll
  for (int ks = 0; ks < 2; ks++)
    #pragma unroll
    for (int i = 0; i < 4; i++) {
      int ra = wm * 64 + i * 16 + lr;
      offA[ks][i] = ra * 64 + ((ks * 4 + lk + ra) & 7) * 8;
      int rb = wn * 64 + i * 16 + lr;
      offB[ks][i] = rb * 64 + ((ks * 4 + lk + rb) & 7) * 8;
    }

  frag_cd acc[4][4];
  #pragma unroll
  for (int i = 0; i < 4; i++)
    #pragma unroll
    for (int j = 0; j < 4; j++)
      acc[i][j] = (frag_cd){0.f, 0.f, 0.f, 0.f};

  for (int kk = 0; kk < 4; kk++) {      // K=256, BK=64
    #pragma unroll
    for (int q = 0; q < 4; q++) gl2lds16(aSrc[q] + kk * 64, aDst[q]);
    #pragma unroll
    for (int q = 0; q < 4; q++) gl2lds16(bSrc[q] + kk * 64, bDst[q]);
    __syncthreads();                    // drains vmcnt -> tile resident in LDS
    #pragma unroll
    for (int ks = 0; ks < 2; ks++) {
      frag_ab a[4], b[4];
      #pragma unroll
      for (int i = 0; i < 4; i++) a[i] = *(const frag_ab*)(sA + offA[ks][i]);
      #pragma unroll
      for (int j = 0; j < 4; j++) b[j] = *(const frag_ab*)(sB + offB[ks][j]);
      #pragma unroll
      for (int i = 0; i < 4; i++)
        #pragma unroll
        for (int j = 0; j < 4; j++)
          acc[i][j] = __builtin_amdgcn_mfma_f32_16x16x32_bf16(a[i], b[j], acc[i][j], 0, 0, 0);
    }
    __syncthreads();                    // tile consumed before overwrite
  }

  // epilogue: C/D layout col=lane&15, row=(lane>>4)*4+reg  [m89-verified]
  #pragma unroll
  for (int i = 0; i < 4; i++) {
    #pragma unroll
    for (int rr = 0; rr < 4; rr++) {
      int m = wm * 64 + i * 16 + lk * 4 + rr;
      if (mt * 128 + m < ne) {             // pad rows: no store
        int tokn = sTok[m];
        float g = sG[m];
        float* orow = out + (size_t)tokn * 256 + nt * 128;
        #pragma unroll
        for (int j = 0; j < 4; j++) {
          int col = wn * 64 + j * 16 + lr;
          float v = g * (acc[i][j][rr] - sCor[col]);
          if (mode) v += orow[col];
          orow[col] = v;
        }
      }
    }
  }
}

extern "C" void kernel_launch(void* const* d_in, const int* in_sizes, int n_in,
                              void* d_out, int out_size, void* d_ws, size_t ws_size,
                              hipStream_t stream) {
  const float* x    = (const float*)d_in[0];  // [N][D]
  const float* wg   = (const float*)d_in[1];  // [D][E]
  const float* bias = (const float*)d_in[2];  // [E][D]
  const float* w    = (const float*)d_in[3];  // [E][OUT][D]
  float* out = (float*)d_out;
  char* ws = (char*)d_ws;

  // total ws usage: ~36.5 MB (round-1 proved >=39.6 MB available)
  unsigned short* xb = (unsigned short*)(ws);                 // 33,554,432 B
  unsigned short* Wb = (unsigned short*)(ws + 33554432);      //  1,048,576 B
  float* c           = (float*)(ws + 34603008);               //      8,192 B
  int* meta          = (int*)(ws + 34611200);                 //        256 B
  int* routeE        = (int*)(ws + 34611456);                 //    262,144 B
  float* routeG      = (float*)(ws + 34873600);               //    524,288 B
  int* srcTok1       = (int*)(ws + 35397888);                 //    266,240 B (66560 slots)
  float* srcGate1    = (float*)(ws + 35664128);               //    266,240 B
  int* srcTok2       = (int*)(ws + 35930368);                 //    266,240 B
  float* srcGate2    = (float*)(ws + 36196608);               //    266,240 B -> ends 36,462,848

  hipLaunchKernelGGL(k_prep,    dim3(1024), dim3(256),  0, stream, w, bias, Wb, c, meta);
  hipLaunchKernelGGL(k_gating,  dim3(512),  dim3(256),  0, stream, x, wg, xb, routeE, routeG, meta);
  hipLaunchKernelGGL(k_scan,    dim3(1),    dim3(64),   0, stream, meta);
  hipLaunchKernelGGL(k_scatter, dim3(64),   dim3(1024), 0, stream, routeE, routeG, meta,
                     srcTok1, srcGate1, srcTok2, srcGate2);
  hipLaunchKernelGGL(k_gemm,    dim3(1040), dim3(256),  0, stream, xb, Wb,
                     meta,     meta + 16, srcTok1, srcGate1, c, out, 0);
  hipLaunchKernelGGL(k_gemm,    dim3(1040), dim3(256),  0, stream, xb, Wb,
                     meta + 8, meta + 24, srcTok2, srcGate2, c, out, 1);
}